// Round 2
// baseline (231.573 us; speedup 1.0000x reference)
//
#include <hip/hip_runtime.h>
#include <math.h>

#define N_SAMPLES 16384
#define FEAT 2048
#define NCLS 1000
#define MAIN_BLOCKS 2048  // 8192 waves, 2 rows each

// ---------------- workspace layout (floats/ints) ----------------
// sums    : float[NCLS*FEAT]   per-class feature sums
// snorm   : float[1024]        ||sums_c||
// counts  : int[1024]
// overall : float[FEAT]        sum over all samples  <- memset from here
// scalars : float[4]           {st_sum, sw_sum, pad, pad}
// done    : int[1]

// One block per class: find own rows by scanning labels (deterministic chunked
// compaction), sum rows coalesced (float4, 2-row unroll), write sums + snorm +
// counts, atomicAdd into overall.
__global__ __launch_bounds__(256) void class_sum_kernel(
    const float* __restrict__ feat, const int* __restrict__ labels,
    float* __restrict__ sums, float* __restrict__ snorm,
    int* __restrict__ counts, float* __restrict__ overall) {
  const int c = blockIdx.x, t = threadIdx.x;
  const int lane = t & 63, w = t >> 6;
  __shared__ int list[320];
  __shared__ int wsum[4];
  __shared__ float red[4];

  // pass 1: count matches in my contiguous chunk of 64 labels (int4 loads)
  const int base = t * 64;
  const int4* lb = (const int4*)(labels + base);
  int myc = 0;
#pragma unroll
  for (int j = 0; j < 16; ++j) {
    int4 q = lb[j];
    myc += (q.x == c) + (q.y == c) + (q.z == c) + (q.w == c);
  }
  // inclusive wave scan of myc
  int v = myc;
  for (int off = 1; off < 64; off <<= 1) {
    int p = __shfl_up(v, off);
    if (lane >= off) v += p;
  }
  if (lane == 63) wsum[w] = v;
  __syncthreads();
  int wbase = 0;
  for (int i = 0; i < w; ++i) wbase += wsum[i];
  int pos = wbase + v - myc;  // exclusive prefix for this thread
  const int n = wsum[0] + wsum[1] + wsum[2] + wsum[3];
  // pass 2: write matching indices in sorted order (L1-hot re-read)
#pragma unroll
  for (int j = 0; j < 16; ++j) {
    int4 q = lb[j];
    int idx = base + 4 * j;
    if (q.x == c) list[pos++] = idx;
    if (q.y == c) list[pos++] = idx + 1;
    if (q.z == c) list[pos++] = idx + 2;
    if (q.w == c) list[pos++] = idx + 3;
  }
  __syncthreads();
  if (t == 0) counts[c] = n;

  // row accumulation: thread t owns dims [4t..4t+3] and [1024+4t..1024+4t+3]
  float a0 = 0, a1 = 0, a2 = 0, a3 = 0, b0 = 0, b1 = 0, b2 = 0, b3 = 0;
  float c0 = 0, c1 = 0, c2 = 0, c3 = 0, d0 = 0, d1 = 0, d2 = 0, d3 = 0;
  int r = 0;
  for (; r + 1 < n; r += 2) {
    const float4* r0 = (const float4*)(feat + (size_t)list[r] * FEAT);
    const float4* r1 = (const float4*)(feat + (size_t)list[r + 1] * FEAT);
    float4 v0 = r0[t], v1 = r0[t + 256];
    float4 u0 = r1[t], u1 = r1[t + 256];
    a0 += v0.x; a1 += v0.y; a2 += v0.z; a3 += v0.w;
    b0 += v1.x; b1 += v1.y; b2 += v1.z; b3 += v1.w;
    c0 += u0.x; c1 += u0.y; c2 += u0.z; c3 += u0.w;
    d0 += u1.x; d1 += u1.y; d2 += u1.z; d3 += u1.w;
  }
  if (r < n) {
    const float4* r0 = (const float4*)(feat + (size_t)list[r] * FEAT);
    float4 v0 = r0[t], v1 = r0[t + 256];
    a0 += v0.x; a1 += v0.y; a2 += v0.z; a3 += v0.w;
    b0 += v1.x; b1 += v1.y; b2 += v1.z; b3 += v1.w;
  }
  a0 += c0; a1 += c1; a2 += c2; a3 += c3;
  b0 += d0; b1 += d1; b2 += d2; b3 += d3;

  float4* sr = (float4*)(sums + (size_t)c * FEAT);
  sr[t] = make_float4(a0, a1, a2, a3);
  sr[t + 256] = make_float4(b0, b1, b2, b3);

  // overall += sums_c (device-scope f32 atomics, 8 per thread)
  atomicAdd(&overall[4 * t + 0], a0);
  atomicAdd(&overall[4 * t + 1], a1);
  atomicAdd(&overall[4 * t + 2], a2);
  atomicAdd(&overall[4 * t + 3], a3);
  atomicAdd(&overall[1024 + 4 * t + 0], b0);
  atomicAdd(&overall[1024 + 4 * t + 1], b1);
  atomicAdd(&overall[1024 + 4 * t + 2], b2);
  atomicAdd(&overall[1024 + 4 * t + 3], b3);

  // ||sums_c||
  float sq = a0 * a0 + a1 * a1 + a2 * a2 + a3 * a3 +
             b0 * b0 + b1 * b1 + b2 * b2 + b3 * b3;
  for (int off = 32; off; off >>= 1) sq += __shfl_xor(sq, off);
  if (lane == 0) red[w] = sq;
  __syncthreads();
  if (t == 0) snorm[c] = sqrtf(red[0] + red[1] + red[2] + red[3]);
}

// One wave per 2 rows: dot(x, overall), dot(x, sums[label]), ||x||^2, and
// ||overall||^2 inline. Last block finalizes output.
__global__ __launch_bounds__(256) void main_kernel(
    const float* __restrict__ feat, const int* __restrict__ labels,
    const float* __restrict__ sums, const float* __restrict__ snorm,
    const float* __restrict__ overall, const int* __restrict__ counts,
    float* __restrict__ scalars, int* __restrict__ done,
    float* __restrict__ out) {
  const int t = threadIdx.x, w = t >> 6, lane = t & 63;
  const float4* ov = (const float4*)overall;
  const float invN2 = 1.f / ((float)N_SAMPLES * (float)N_SAMPLES);
  float st_acc = 0.f, sw_acc = 0.f;
#pragma unroll
  for (int rep = 0; rep < 2; ++rep) {
    const int row = blockIdx.x * 4 + w + rep * (MAIN_BLOCKS * 4);
    const int l = labels[row];
    const float4* xr = (const float4*)(feat + (size_t)row * FEAT);
    const float4* srw = (const float4*)(sums + (size_t)l * FEAT);
    float dxo = 0.f, dxs = 0.f, nx2 = 0.f, ov2 = 0.f;
#pragma unroll
    for (int k = 0; k < 8; ++k) {
      float4 x = xr[lane + 64 * k];
      float4 s = srw[lane + 64 * k];
      float4 o = ov[lane + 64 * k];
      dxo += x.x * o.x + x.y * o.y + x.z * o.z + x.w * o.w;
      dxs += x.x * s.x + x.y * s.y + x.z * s.z + x.w * s.w;
      nx2 += x.x * x.x + x.y * x.y + x.z * x.z + x.w * x.w;
      ov2 += o.x * o.x + o.y * o.y + o.z * o.z + o.w * o.w;
    }
    for (int off = 32; off; off >>= 1) {
      dxo += __shfl_xor(dxo, off);
      dxs += __shfl_xor(dxs, off);
      nx2 += __shfl_xor(nx2, off);
      ov2 += __shfl_xor(ov2, off);
    }
    if (lane == 0) {
      float nx = sqrtf(nx2);
      float ovn = sqrtf(ov2);
      float cnt = (float)counts[l];
      // cdist(x, mean_all) = 1 - dot(x,S)/||x|| * ||S||/N^2
      float t1 = 1.f - dxo * ovn * invN2 / nx;
      // d = 1 - dot(x, sums_l)*||sums_l|| / (cnt^2 * ||x||)
      float t2 = 1.f - dxs * snorm[l] / (cnt * cnt * nx);
      st_acc += t1 * t1;
      sw_acc += t2 * t2;
    }
  }
  __shared__ float red[8];
  if (lane == 0) { red[w] = st_acc; red[4 + w] = sw_acc; }
  __syncthreads();
  if (t == 0) {
    atomicAdd(&scalars[0], red[0] + red[1] + red[2] + red[3]);
    atomicAdd(&scalars[1], red[4] + red[5] + red[6] + red[7]);
  }
  // last block finalizes
  __shared__ int last;
  if (t == 0) {
    __threadfence();
    last = atomicAdd(done, 1);
  }
  __syncthreads();
  if (t == 0 && last == MAIN_BLOCKS - 1) {
    float stv = atomicAdd(&scalars[0], 0.f) / (float)N_SAMPLES;
    float swv = atomicAdd(&scalars[1], 0.f) / ((float)N_SAMPLES * (float)NCLS);
    out[0] = stv;
    out[1] = swv;
    out[2] = stv - swv;
  }
}

extern "C" void kernel_launch(void* const* d_in, const int* in_sizes, int n_in,
                              void* d_out, int out_size, void* d_ws, size_t ws_size,
                              hipStream_t stream) {
  const float* feat = (const float*)d_in[0];
  const int* labels = (const int*)d_in[1];
  float* out = (float*)d_out;

  float* sums = (float*)d_ws;                   // NCLS*FEAT
  float* snorm = sums + (size_t)NCLS * FEAT;    // 1024
  int* counts = (int*)(snorm + 1024);           // 1024
  float* overall = (float*)(counts + 1024);     // FEAT  <- memset from here
  float* scalars = overall + FEAT;              // 4
  int* done = (int*)(scalars + 4);              // 1

  // zero overall + scalars + done in one async memset (graph-capture safe)
  hipMemsetAsync(overall, 0, (FEAT + 4 + 1) * sizeof(float), stream);
  class_sum_kernel<<<NCLS, 256, 0, stream>>>(feat, labels, sums, snorm, counts,
                                             overall);
  main_kernel<<<MAIN_BLOCKS, 256, 0, stream>>>(feat, labels, sums, snorm, overall,
                                               counts, scalars, done, out);
}

// Round 3
// 94.081 us; speedup vs baseline: 2.4614x; 2.4614x over previous
//
#include <hip/hip_runtime.h>
#include <math.h>

#define N_SAMPLES 16384
#define FEAT 2048
#define NCLS 1000
#define CPAD 1024
#define MAIN_BLOCKS 2048

// ---------------- workspace layout ----------------
// sums     : float[NCLS*FEAT]
// snorm    : float[CPAD]
// overall  : float[FEAT]          (final summed vector, written by ovnorm)
// part_ov  : float[8*FEAT]        (8 plain partial vectors, no atomics)
// pst/psw  : float[MAIN_BLOCKS]   (per-block partials from main)
// counts   : int[CPAD]            <- memset zero region starts here
// scalars  : float[4]             {||overall||, -, -, -}
// offsets  : int[CPAD]
// cursor   : int[CPAD]
// perm     : int[N_SAMPLES]

__global__ void hist_kernel(const int* __restrict__ labels, int* __restrict__ counts) {
  int i = blockIdx.x * blockDim.x + threadIdx.x;
  if (i < N_SAMPLES) atomicAdd(&counts[labels[i]], 1);
}

// exclusive scan over CPAD=1024 counts, single block of 1024 threads
__global__ void scan_kernel(const int* __restrict__ counts, int* __restrict__ offsets,
                            int* __restrict__ cursor) {
  __shared__ int buf0[CPAD], buf1[CPAD];
  int t = threadIdx.x;
  buf0[t] = counts[t];
  __syncthreads();
  int* src = buf0;
  int* dst = buf1;
  for (int off = 1; off < CPAD; off <<= 1) {
    dst[t] = src[t] + (t >= off ? src[t - off] : 0);
    __syncthreads();
    int* tmp = src; src = dst; dst = tmp;
  }
  int excl = (t == 0) ? 0 : src[t - 1];
  offsets[t] = excl;
  cursor[t] = excl;
}

__global__ void scatter_kernel(const int* __restrict__ labels, int* __restrict__ cursor,
                               int* __restrict__ perm) {
  int i = blockIdx.x * blockDim.x + threadIdx.x;
  if (i < N_SAMPLES) {
    int pos = atomicAdd(&cursor[labels[i]], 1);
    perm[pos] = i;
  }
}

// one block per class: sum own rows (coalesced float4, 4-row unroll),
// write sums + ||sums||. No atomics, no label rescans.
__global__ __launch_bounds__(256) void class_sum_kernel(
    const float* __restrict__ feat, const int* __restrict__ offsets,
    const int* __restrict__ counts, const int* __restrict__ perm,
    float* __restrict__ sums, float* __restrict__ snorm) {
  const int c = blockIdx.x, t = threadIdx.x;
  const int beg = offsets[c], n = counts[c];
  float a0 = 0, a1 = 0, a2 = 0, a3 = 0, b0 = 0, b1 = 0, b2 = 0, b3 = 0;
  int r = 0;
  for (; r + 4 <= n; r += 4) {
    const float4* r0 = (const float4*)(feat + (size_t)perm[beg + r] * FEAT);
    const float4* r1 = (const float4*)(feat + (size_t)perm[beg + r + 1] * FEAT);
    const float4* r2 = (const float4*)(feat + (size_t)perm[beg + r + 2] * FEAT);
    const float4* r3 = (const float4*)(feat + (size_t)perm[beg + r + 3] * FEAT);
    float4 v0 = r0[t], w0 = r0[t + 256];
    float4 v1 = r1[t], w1 = r1[t + 256];
    float4 v2 = r2[t], w2 = r2[t + 256];
    float4 v3 = r3[t], w3 = r3[t + 256];
    a0 += (v0.x + v1.x) + (v2.x + v3.x);
    a1 += (v0.y + v1.y) + (v2.y + v3.y);
    a2 += (v0.z + v1.z) + (v2.z + v3.z);
    a3 += (v0.w + v1.w) + (v2.w + v3.w);
    b0 += (w0.x + w1.x) + (w2.x + w3.x);
    b1 += (w0.y + w1.y) + (w2.y + w3.y);
    b2 += (w0.z + w1.z) + (w2.z + w3.z);
    b3 += (w0.w + w1.w) + (w2.w + w3.w);
  }
  for (; r < n; ++r) {
    const float4* r0 = (const float4*)(feat + (size_t)perm[beg + r] * FEAT);
    float4 v0 = r0[t], w0 = r0[t + 256];
    a0 += v0.x; a1 += v0.y; a2 += v0.z; a3 += v0.w;
    b0 += w0.x; b1 += w0.y; b2 += w0.z; b3 += w0.w;
  }
  float4* sr = (float4*)(sums + (size_t)c * FEAT);
  sr[t] = make_float4(a0, a1, a2, a3);
  sr[t + 256] = make_float4(b0, b1, b2, b3);
  float sq = a0 * a0 + a1 * a1 + a2 * a2 + a3 * a3 +
             b0 * b0 + b1 * b1 + b2 * b2 + b3 * b3;
  for (int off = 32; off; off >>= 1) sq += __shfl_xor(sq, off);
  __shared__ float red[4];
  int w = t >> 6, lane = t & 63;
  if (lane == 0) red[w] = sq;
  __syncthreads();
  if (t == 0) snorm[c] = sqrtf(red[0] + red[1] + red[2] + red[3]);
}

// 64 blocks = 8 d-chunks x 8 c-chunks; plain stores to part_ov (no atomics)
__global__ __launch_bounds__(256) void overall_part_kernel(
    const float* __restrict__ sums, float* __restrict__ part_ov) {
  int dchunk = blockIdx.x & 7;
  int cchunk = blockIdx.x >> 3;
  int d = dchunk * 256 + threadIdx.x;
  float acc = 0.f;
  int cbeg = cchunk * 125, cend = cbeg + 125;
  for (int c = cbeg; c < cend; ++c) acc += sums[(size_t)c * FEAT + d];
  part_ov[cchunk * FEAT + d] = acc;
}

// fold 8 partials -> overall, and compute ||overall|| -> scalars[0]
__global__ __launch_bounds__(256) void ovnorm_kernel(
    const float* __restrict__ part_ov, float* __restrict__ overall,
    float* __restrict__ scalars) {
  int t = threadIdx.x;
  float sq = 0.f;
  for (int k = 0; k < 8; ++k) {
    int d = t + 256 * k;
    float v = 0.f;
    for (int p = 0; p < 8; ++p) v += part_ov[p * FEAT + d];
    overall[d] = v;
    sq += v * v;
  }
  for (int off = 32; off; off >>= 1) sq += __shfl_xor(sq, off);
  __shared__ float red[4];
  int w = t >> 6, lane = t & 63;
  if (lane == 0) red[w] = sq;
  __syncthreads();
  if (t == 0) scalars[0] = sqrtf(red[0] + red[1] + red[2] + red[3]);
}

// one wave per row (2 rows per wave): dot(x,overall), dot(x,sums[l]), ||x||^2.
// Per-block partials via plain stores.
__global__ __launch_bounds__(256) void main_kernel(
    const float* __restrict__ feat, const int* __restrict__ labels,
    const float* __restrict__ sums, const float* __restrict__ snorm,
    const float* __restrict__ overall, const int* __restrict__ counts,
    const float* __restrict__ scalars, float* __restrict__ pst,
    float* __restrict__ psw) {
  const int t = threadIdx.x, w = t >> 6, lane = t & 63;
  const float4* ov = (const float4*)overall;
  const float invN2 = 1.f / ((float)N_SAMPLES * (float)N_SAMPLES);
  const float ovn = scalars[0];
  float st_acc = 0.f, sw_acc = 0.f;
#pragma unroll
  for (int rep = 0; rep < 2; ++rep) {
    const int row = blockIdx.x * 4 + w + rep * (MAIN_BLOCKS * 4);
    const int l = labels[row];
    const float4* xr = (const float4*)(feat + (size_t)row * FEAT);
    const float4* srw = (const float4*)(sums + (size_t)l * FEAT);
    float dxo = 0.f, dxs = 0.f, nx2 = 0.f;
#pragma unroll
    for (int k = 0; k < 8; ++k) {
      float4 x = xr[lane + 64 * k];
      float4 s = srw[lane + 64 * k];
      float4 o = ov[lane + 64 * k];
      dxo += x.x * o.x + x.y * o.y + x.z * o.z + x.w * o.w;
      dxs += x.x * s.x + x.y * s.y + x.z * s.z + x.w * s.w;
      nx2 += x.x * x.x + x.y * x.y + x.z * x.z + x.w * x.w;
    }
    for (int off = 32; off; off >>= 1) {
      dxo += __shfl_xor(dxo, off);
      dxs += __shfl_xor(dxs, off);
      nx2 += __shfl_xor(nx2, off);
    }
    if (lane == 0) {
      float nx = sqrtf(nx2);
      float cnt = (float)counts[l];
      float t1 = 1.f - dxo * ovn * invN2 / nx;
      float t2 = 1.f - dxs * snorm[l] / (cnt * cnt * nx);
      st_acc += t1 * t1;
      sw_acc += t2 * t2;
    }
  }
  __shared__ float red[8];
  if (lane == 0) { red[w] = st_acc; red[4 + w] = sw_acc; }
  __syncthreads();
  if (t == 0) {
    pst[blockIdx.x] = red[0] + red[1] + red[2] + red[3];
    psw[blockIdx.x] = red[4] + red[5] + red[6] + red[7];
  }
}

// single block: reduce 2048+2048 partials, write the 3 outputs
__global__ __launch_bounds__(1024) void final_kernel(
    const float* __restrict__ pst, const float* __restrict__ psw,
    float* __restrict__ out) {
  int t = threadIdx.x;
  float st = pst[t] + pst[t + 1024];
  float sw = psw[t] + psw[t + 1024];
  for (int off = 32; off; off >>= 1) {
    st += __shfl_xor(st, off);
    sw += __shfl_xor(sw, off);
  }
  __shared__ float rs[16], rw[16];
  int w = t >> 6, lane = t & 63;
  if (lane == 0) { rs[w] = st; rw[w] = sw; }
  __syncthreads();
  if (t == 0) {
    float s = 0.f, q = 0.f;
    for (int i = 0; i < 16; ++i) { s += rs[i]; q += rw[i]; }
    float stv = s / (float)N_SAMPLES;
    float swv = q / ((float)N_SAMPLES * (float)NCLS);
    out[0] = stv;
    out[1] = swv;
    out[2] = stv - swv;
  }
}

extern "C" void kernel_launch(void* const* d_in, const int* in_sizes, int n_in,
                              void* d_out, int out_size, void* d_ws, size_t ws_size,
                              hipStream_t stream) {
  const float* feat = (const float*)d_in[0];
  const int* labels = (const int*)d_in[1];
  float* out = (float*)d_out;

  float* sums = (float*)d_ws;                    // NCLS*FEAT
  float* snorm = sums + (size_t)NCLS * FEAT;     // CPAD
  float* overall = snorm + CPAD;                 // FEAT
  float* part_ov = overall + FEAT;               // 8*FEAT
  float* pst = part_ov + 8 * FEAT;               // MAIN_BLOCKS
  float* psw = pst + MAIN_BLOCKS;                // MAIN_BLOCKS
  int* counts = (int*)(psw + MAIN_BLOCKS);       // CPAD  <- zero from here
  float* scalars = (float*)(counts + CPAD);      // 4
  int* offsets = (int*)(scalars + 4);            // CPAD
  int* cursor = offsets + CPAD;                  // CPAD
  int* perm = cursor + CPAD;                     // N_SAMPLES

  hipMemsetAsync(counts, 0, (CPAD + 4) * sizeof(int), stream);
  hist_kernel<<<64, 256, 0, stream>>>(labels, counts);
  scan_kernel<<<1, 1024, 0, stream>>>(counts, offsets, cursor);
  scatter_kernel<<<64, 256, 0, stream>>>(labels, cursor, perm);
  class_sum_kernel<<<NCLS, 256, 0, stream>>>(feat, offsets, counts, perm, sums, snorm);
  overall_part_kernel<<<64, 256, 0, stream>>>(sums, part_ov);
  ovnorm_kernel<<<1, 256, 0, stream>>>(part_ov, overall, scalars);
  main_kernel<<<MAIN_BLOCKS, 256, 0, stream>>>(feat, labels, sums, snorm, overall,
                                               counts, scalars, pst, psw);
  final_kernel<<<1, 1024, 0, stream>>>(pst, psw, out);
}